// Round 3
// baseline (289.508 us; speedup 1.0000x reference)
//
#include <hip/hip_runtime.h>
#include <stdint.h>

typedef __attribute__((ext_vector_type(4))) float f32x4;
typedef __attribute__((ext_vector_type(8))) _Float16 f16x8;

#define HIDDEN 1024
#define SEQ 2048
#define NB 4

__device__ inline unsigned short f2h_bits(float f) {
    _Float16 h = (_Float16)f;
    return __builtin_bit_cast(unsigned short, h);
}

__device__ inline void gload16(const void* g, void* l) {
    __builtin_amdgcn_global_load_lds(
        (const __attribute__((address_space(1))) unsigned int*)g,
        (__attribute__((address_space(3))) unsigned int*)l,
        16, 0, 0);
}

template<int N> __device__ inline void waitvm() {
    static_assert(N == 3 || N == 4, "unsupported vmcnt");
    if constexpr (N == 3) asm volatile("s_waitcnt vmcnt(3)" ::: "memory");
    else                  asm volatile("s_waitcnt vmcnt(4)" ::: "memory");
}

// C[M,N] = A[M,K] @ Bt[N,K]^T (+bias). fp16 inputs, f32 accum.
// 3-stage LDS pipeline, BK=32, prefetch distance 2, counted vmcnt (never 0 in loop).
// Wave grid WM x WN; per-wave output (MR*16) x (NR*16).
// BIAS_MODE: 0 none, 1 bias[col], 2 bias[row].
template<int BM, int BN, int WM, int WN, int BIAS_MODE, bool OUT_F16>
__global__ __launch_bounds__(WM * WN * 64) void gemm_pipe(
    const unsigned short* __restrict__ A, int lda,
    const unsigned short* __restrict__ Bt, int ldb,
    const float* __restrict__ bias,
    void* __restrict__ Cptr, int ldc, int K,
    long long aBatch, long long bBatch, long long cBatch)
{
    constexpr int THREADS = WM * WN * 64;
    constexpr int MR = BM / (WM * 16);
    constexpr int NR = BN / (WN * 16);
    constexpr int SA = (BM * 4) / THREADS;  // 16B chunks of A-tile per thread
    constexpr int SB = (BN * 4) / THREADS;
    constexpr int SN = SA + SB;
    static_assert((BM * 4) % THREADS == 0 && (BN * 4) % THREADS == 0, "stage split");

    __shared__ unsigned short La[3][BM][32];
    __shared__ unsigned short Lb[3][BN][32];

    const int tid = threadIdx.x, lane = tid & 63, wave = tid >> 6;
    const int wr = wave / WN, wc = wave % WN;
    const int fr = lane & 15, fq = lane >> 4;

    const long long bz = blockIdx.z;
    const unsigned short* Ab = A + bz * aBatch + (long long)(blockIdx.y * BM) * lda;
    const unsigned short* Bb = Bt + bz * bBatch + (long long)(blockIdx.x * BN) * ldb;

    // Per-thread stage sources (at k0=0) and per-wave-uniform LDS byte offsets.
    // Chunk c covers LDS row c>>2, 16B slot c&3; HW adds lane*16 to the LDS base.
    const unsigned short* sA[SA]; int oA[SA];
    #pragma unroll
    for (int i = 0; i < SA; ++i) {
        int c = i * THREADS + tid;
        sA[i] = Ab + (long long)(c >> 2) * lda + (c & 3) * 8;
        oA[i] = (i * THREADS + wave * 64) * 16;
    }
    const unsigned short* sB[SB]; int oB[SB];
    #pragma unroll
    for (int i = 0; i < SB; ++i) {
        int c = i * THREADS + tid;
        sB[i] = Bb + (long long)(c >> 2) * ldb + (c & 3) * 8;
        oB[i] = (i * THREADS + wave * 64) * 16;
    }

    auto stage = [&](int buf, int k0) {
        #pragma unroll
        for (int i = 0; i < SA; ++i)
            gload16(sA[i] + k0, (char*)&La[buf][0][0] + oA[i]);
        #pragma unroll
        for (int i = 0; i < SB; ++i)
            gload16(sB[i] + k0, (char*)&Lb[buf][0][0] + oB[i]);
    };

    const int NT = K / 32;

    // Prologue: stage tiles 0 and 1; wait for tile 0 (tile 1 stays in flight).
    stage(0, 0);
    stage(1, 32);
    __builtin_amdgcn_sched_barrier(0);
    waitvm<SN>();
    __builtin_amdgcn_s_barrier();
    __builtin_amdgcn_sched_barrier(0);

    f32x4 acc[MR][NR] = {};
    int bsel = 0;

    for (int t = 0; t < NT; ++t) {
        f16x8 af[MR], bf[NR];
        #pragma unroll
        for (int m = 0; m < MR; ++m)
            af[m] = *(const f16x8*)&La[bsel][wr * (MR * 16) + m * 16 + fr][fq * 8];
        #pragma unroll
        for (int n = 0; n < NR; ++n)
            bf[n] = *(const f16x8*)&Lb[bsel][wc * (NR * 16) + n * 16 + fr][fq * 8];

        // Prefetch tile t+2 into the buffer tile t-1 vacated (all reads of t-1
        // completed before the barrier that ended iteration t-1).
        if (t + 2 < NT) {
            int b2 = bsel - 1; if (b2 < 0) b2 += 3;   // (bsel+2)%3
            stage(b2, (t + 2) * 32);
        }

        __builtin_amdgcn_s_setprio(1);
        #pragma unroll
        for (int m = 0; m < MR; ++m)
            #pragma unroll
            for (int n = 0; n < NR; ++n)
                acc[m][n] = __builtin_amdgcn_mfma_f32_16x16x32_f16(af[m], bf[n], acc[m][n], 0, 0, 0);
        __builtin_amdgcn_s_setprio(0);

        __builtin_amdgcn_sched_barrier(0);
        waitvm<SN>();                    // drains tile t+1's loads only; t+2's stay in flight
        __builtin_amdgcn_s_barrier();
        __builtin_amdgcn_sched_barrier(0);

        bsel = (bsel == 2) ? 0 : bsel + 1;
    }

    // Epilogue. C/D layout: col = lane&15, row = (lane>>4)*4 + i.
    const int row0 = blockIdx.y * BM + wr * (MR * 16);
    const int col0 = blockIdx.x * BN + wc * (NR * 16);
    #pragma unroll
    for (int m = 0; m < MR; ++m)
        #pragma unroll
        for (int n = 0; n < NR; ++n)
            #pragma unroll
            for (int i = 0; i < 4; ++i) {
                int r = row0 + m * 16 + fq * 4 + i;
                int c = col0 + n * 16 + fr;
                float val = acc[m][n][i];
                if constexpr (BIAS_MODE == 1) val += bias[c];
                if constexpr (BIAS_MODE == 2) val += bias[r];
                if constexpr (OUT_F16)
                    ((unsigned short*)Cptr + bz * cBatch)[(long long)r * ldc + c] = f2h_bits(val);
                else
                    ((float*)Cptr + bz * cBatch)[(long long)r * ldc + c] = val;
            }
}

// x (f32) -> fp16 bits, 8 elems/thread
__global__ __launch_bounds__(256) void cvt_f32_f16(const float* __restrict__ in,
                                                   unsigned short* __restrict__ out, int n8)
{
    int i = blockIdx.x * blockDim.x + threadIdx.x;
    if (i >= n8) return;
    const float4* p = (const float4*)in + (long long)i * 2;
    float4 a = p[0], b = p[1];
    ushort4 o0, o1;
    o0.x = f2h_bits(a.x); o0.y = f2h_bits(a.y); o0.z = f2h_bits(a.z); o0.w = f2h_bits(a.w);
    o1.x = f2h_bits(b.x); o1.y = f2h_bits(b.y); o1.z = f2h_bits(b.z); o1.w = f2h_bits(b.w);
    ushort4* o = (ushort4*)out + (long long)i * 2;
    o[0] = o0; o[1] = o1;
}

// out[c][r] = (fp16) in[r][c]
__global__ void transpose_cvt(const float* __restrict__ in, unsigned short* __restrict__ out,
                              int R, int C)
{
    __shared__ unsigned short t[32][33];
    const int bx = blockIdx.x * 32;
    const int by = blockIdx.y * 32;
    const int xT = threadIdx.x, yT = threadIdx.y;  // block (32,8)
    #pragma unroll
    for (int i = 0; i < 32; i += 8)
        t[yT + i][xT] = f2h_bits(in[(long long)(by + yT + i) * C + bx + xT]);
    __syncthreads();
    #pragma unroll
    for (int i = 0; i < 32; i += 8)
        out[(long long)(bx + yT + i) * R + by + xT] = t[xT][yT + i];
}

__global__ void concat_bias(const float* __restrict__ bq, const float* __restrict__ bk,
                            float* __restrict__ cb)
{
    int i = threadIdx.x;  // 1024 threads
    cb[i] = bq[i];
    cb[HIDDEN + i] = bk[i];
}

// One block (256 threads) per row of 2048 f32 scores.
// Writes P (fp16 bits) in place over the first half of the same row.
__global__ __launch_bounds__(256) void softmax_inplace(float* __restrict__ S)
{
    const int tid = threadIdx.x;
    float* row = S + (long long)blockIdx.x * SEQ;
    float4 a = ((const float4*)row)[tid];
    float4 b = ((const float4*)row)[tid + 256];
    float vv[8] = {a.x, a.y, a.z, a.w, b.x, b.y, b.z, b.w};

    float mx = vv[0];
    #pragma unroll
    for (int j = 1; j < 8; ++j) mx = fmaxf(mx, vv[j]);
    #pragma unroll
    for (int o = 32; o > 0; o >>= 1) mx = fmaxf(mx, __shfl_xor(mx, o));
    __shared__ float redm[4], reds[4];
    if ((tid & 63) == 0) redm[tid >> 6] = mx;
    __syncthreads();
    mx = fmaxf(fmaxf(redm[0], redm[1]), fmaxf(redm[2], redm[3]));

    float ev[8], sum = 0.f;
    #pragma unroll
    for (int j = 0; j < 8; ++j) { ev[j] = __expf(vv[j] - mx); sum += ev[j]; }
    #pragma unroll
    for (int o = 32; o > 0; o >>= 1) sum += __shfl_xor(sum, o);
    if ((tid & 63) == 0) reds[tid >> 6] = sum;
    __syncthreads();
    sum = reds[0] + reds[1] + reds[2] + reds[3];
    float inv = 1.0f / sum;

    unsigned short* rb = (unsigned short*)row;
    ushort4 o0, o1;
    o0.x = f2h_bits(ev[0] * inv); o0.y = f2h_bits(ev[1] * inv);
    o0.z = f2h_bits(ev[2] * inv); o0.w = f2h_bits(ev[3] * inv);
    o1.x = f2h_bits(ev[4] * inv); o1.y = f2h_bits(ev[5] * inv);
    o1.z = f2h_bits(ev[6] * inv); o1.w = f2h_bits(ev[7] * inv);
    *(ushort4*)&rb[(long long)tid * 4] = o0;
    *(ushort4*)&rb[((long long)tid + 256) * 4] = o1;
}

extern "C" void kernel_launch(void* const* d_in, const int* in_sizes, int n_in,
                              void* d_out, int out_size, void* d_ws, size_t ws_size,
                              hipStream_t stream)
{
    (void)in_sizes; (void)n_in; (void)out_size; (void)ws_size;
    const float* x  = (const float*)d_in[0];
    const float* Wq = (const float*)d_in[1];
    const float* bq = (const float*)d_in[2];
    const float* Wk = (const float*)d_in[3];
    const float* bk = (const float*)d_in[4];
    const float* Wv = (const float*)d_in[5];
    const float* bv = (const float*)d_in[6];
    float* out = (float*)d_out;

    char* ws = (char*)d_ws;
    const long long MTOT = (long long)NB * SEQ;  // 8192
    size_t off = 0;
    auto take = [&](size_t b){ size_t p = off; off += (b + 255) & ~(size_t)255; return p; };

    unsigned short* qk  = (unsigned short*)(ws + take((size_t)MTOT * 2 * HIDDEN * 2)); // [8192][2048]
    unsigned short* vtC = (unsigned short*)(ws + take((size_t)HIDDEN * MTOT * 2));     // [1024][8192]
    unsigned short* wt  = (unsigned short*)(ws + take((size_t)3 * HIDDEN * HIDDEN * 2));
    float*          cb  = (float*)(ws + take((size_t)2 * HIDDEN * 4));

    // xh (16 MB) lives in the S region until the vt-gemm completes; S reuses it.
    size_t sOff = off;
    unsigned short* xh = (unsigned short*)(ws + sOff);
    float*          S  = (float*)(ws + sOff);

    {
        int n8 = (int)(MTOT * HIDDEN / 8);
        cvt_f32_f16<<<dim3((n8 + 255) / 256), 256, 0, stream>>>(x, xh, n8);
    }
    dim3 tb(32, 8), tg(HIDDEN / 32, HIDDEN / 32);
    transpose_cvt<<<tg, tb, 0, stream>>>(Wq, wt,                       HIDDEN, HIDDEN);
    transpose_cvt<<<tg, tb, 0, stream>>>(Wk, wt +     HIDDEN * HIDDEN, HIDDEN, HIDDEN);
    transpose_cvt<<<tg, tb, 0, stream>>>(Wv, wt + 2 * HIDDEN * HIDDEN, HIDDEN, HIDDEN);
    concat_bias<<<1, 1024, 0, stream>>>(bq, bk, cb);

    // qk[8192][2048] = xh @ [Wq|Wk] + [bq|bk]
    gemm_pipe<128, 128, 2, 2, 1, true><<<dim3(2048 / 128, (unsigned)(MTOT / 128), 1), 256, 0, stream>>>(
        xh, HIDDEN, wt, HIDDEN, cb, qk, 2048, HIDDEN, 0, 0, 0);

    // vtC[1024][8192] = Wv^T @ xh^T + bv (row bias)
    gemm_pipe<128, 128, 2, 2, 2, true><<<dim3((unsigned)(MTOT / 128), HIDDEN / 128, 1), 256, 0, stream>>>(
        wt + 2 * HIDDEN * HIDDEN, HIDDEN, xh, HIDDEN, bv, vtC, (int)MTOT, HIDDEN, 0, 0, 0);

    for (int b = 0; b < NB; ++b) {
        const unsigned short* q  = qk + (long long)b * SEQ * 2048;
        const unsigned short* km = q + HIDDEN;
        float* Sb = S;
        // S = q @ k^T  (f32), 256 blocks
        gemm_pipe<128, 128, 2, 2, 0, false><<<dim3(SEQ / 128, SEQ / 128, 1), 256, 0, stream>>>(
            q, 2048, km, 2048, nullptr, Sb, SEQ, HIDDEN, 0, 0, 0);
        // softmax rows, P fp16 in place (row stride becomes 4096 halfs)
        softmax_inplace<<<dim3(SEQ), 256, 0, stream>>>(Sb);
        // O = P @ vtC^T  (f32 straight to d_out), 256 blocks
        const unsigned short* P = (const unsigned short*)Sb;
        const unsigned short* Bv = vtC + (long long)b * SEQ;
        float* Ob = out + (long long)b * SEQ * HIDDEN;
        gemm_pipe<64, 128, 2, 2, 0, false><<<dim3(HIDDEN / 128, SEQ / 64, 1), 256, 0, stream>>>(
            P, 2 * SEQ, Bv, (int)MTOT, nullptr, Ob, HIDDEN, SEQ, 0, 0, 0);
    }
}

// Round 4
// 204.616 us; speedup vs baseline: 1.4149x; 1.4149x over previous
//
#include <hip/hip_runtime.h>
#include <stdint.h>

typedef __attribute__((ext_vector_type(4))) float f32x4;
typedef __attribute__((ext_vector_type(8))) _Float16 f16x8;

#define HIDDEN 1024
#define SEQ 2048
#define NB 4

__device__ inline unsigned short f2h_bits(float f) {
    _Float16 h = (_Float16)f;
    return __builtin_bit_cast(unsigned short, h);
}

__device__ inline void gload16(const void* g, void* l) {
    __builtin_amdgcn_global_load_lds(
        (const __attribute__((address_space(1))) unsigned int*)g,
        (__attribute__((address_space(3))) unsigned int*)l,
        16, 0, 0);
}

template<int N> __device__ inline void waitvm() {
    if constexpr (N == 0) asm volatile("s_waitcnt vmcnt(0)" ::: "memory");
    else if constexpr (N == 3) asm volatile("s_waitcnt vmcnt(3)" ::: "memory");
    else if constexpr (N == 4) asm volatile("s_waitcnt vmcnt(4)" ::: "memory");
    else if constexpr (N == 6) asm volatile("s_waitcnt vmcnt(6)" ::: "memory");
    else if constexpr (N == 8) asm volatile("s_waitcnt vmcnt(8)" ::: "memory");
    else static_assert(N == 0, "bad vmcnt");
}
__device__ inline void waitlgkm0() { asm volatile("s_waitcnt lgkmcnt(0)" ::: "memory"); }

// ===================== 256-row 8-phase-style GEMM =====================
// C[M,N] = A[M,K] @ Bt[N,K]^T (+bias). fp16 in, f32 accum.
// BM=256 fixed, BN in {128,256}. 512 threads = 8 waves (2M x 4N).
// K-tile = 64 = 2 slices of 32. LDS slice-major, dbuf=2, counted vmcnt.
// Swizzle: physical 16B slot = logical slot ^ ((row>>1)&3)  (involution).
template<int BN, int BIAS_MODE, bool OUT_F16>
__global__ __launch_bounds__(512, 2) void gemm8p(
    const unsigned short* __restrict__ A, int lda,
    const unsigned short* __restrict__ Bt, int ldb,
    const float* __restrict__ bias,
    void* __restrict__ Cptr, int ldc, int K,
    long long aBatch, long long bBatch, long long cBatch)
{
    constexpr int BM = 256;
    constexpr int NRW = BN / 64;          // N-frags per wave: 256->4, 128->2
    constexpr int LA = 2;                 // A gloads/thread/slice (BM/128)
    constexpr int LB = BN / 128;          // 2 or 1
    constexpr int LP = LA + LB;           // loads per slice-pair
    constexpr int ASLICE = BM * 32;       // halfs per A slice
    constexpr int BSLICE = BN * 32;
    constexpr int BOFF = 4 * ASLICE;      // half-offset of B region

    extern __shared__ unsigned short lds[];

    const int tid = threadIdx.x, lane = tid & 63, wave = tid >> 6;
    const int wr = wave >> 2, wc = wave & 3;
    const int fr = lane & 15, fq = lane >> 4;

    const long long bz = blockIdx.z;
    const unsigned short* Ab = A + bz * aBatch + (long long)(blockIdx.y * BM) * lda;
    const unsigned short* Bb = Bt + bz * bBatch + (long long)(blockIdx.x * BN) * ldb;

    // staging: chunk c = i*512+tid; row=c>>2, phys slot=c&3, logical=slot^((row>>1)&3)
    const unsigned short* sA[LA]; int dA[LA];
    #pragma unroll
    for (int i = 0; i < LA; ++i) {
        int c = i * 512 + tid; int r = c >> 2; int ls = (c & 3) ^ ((r >> 1) & 3);
        sA[i] = Ab + (long long)r * lda + ls * 8;
        dA[i] = (i * 512 + wave * 64) * 16;
    }
    const unsigned short* sB[LB]; int dB[LB];
    #pragma unroll
    for (int i = 0; i < LB; ++i) {
        int c = i * 512 + tid; int r = c >> 2; int ls = (c & 3) ^ ((r >> 1) & 3);
        sB[i] = Bb + (long long)r * ldb + ls * 8;
        dB[i] = (i * 512 + wave * 64) * 16;
    }

    auto stage = [&](int t, int ks) {
        int buf = t & 1;
        int aoff = ((buf * 2 + ks) * ASLICE) * 2;          // bytes
        int boff = (BOFF + (buf * 2 + ks) * BSLICE) * 2;
        int kof = t * 64 + ks * 32;
        #pragma unroll
        for (int i = 0; i < LA; ++i) gload16(sA[i] + kof, (char*)lds + aoff + dA[i]);
        #pragma unroll
        for (int i = 0; i < LB; ++i) gload16(sB[i] + kof, (char*)lds + boff + dB[i]);
    };

    const int NT = K / 64;
    // prologue: 3 slice-pairs in flight
    stage(0, 0); stage(0, 1); stage(1, 0);

    f32x4 acc[8][NRW] = {};

    for (int t = 0; t < NT; ++t) {
        #pragma unroll
        for (int ks = 0; ks < 2; ++ks) {
            // gate on this slice-pair's loads (exact counts; never 0 except last tile)
            if (t == NT - 1) { if (ks == 0) waitvm<LP>(); else waitvm<0>(); }
            else waitvm<2 * LP>();
            __builtin_amdgcn_s_barrier();
            __builtin_amdgcn_sched_barrier(0);

            const int buf = t & 1;
            const unsigned short* as = lds + (buf * 2 + ks) * ASLICE;
            const unsigned short* bs = lds + BOFF + (buf * 2 + ks) * BSLICE;
            f16x8 af[8], bf[NRW];
            #pragma unroll
            for (int m = 0; m < 8; ++m) {
                int r = wr * 128 + m * 16 + fr;
                int es = fq ^ ((r >> 1) & 3);
                af[m] = *(const f16x8*)&as[r * 32 + es * 8];
            }
            #pragma unroll
            for (int n = 0; n < NRW; ++n) {
                int r = wc * (BN / 4) + n * 16 + fr;
                int es = fq ^ ((r >> 1) & 3);
                bf[n] = *(const f16x8*)&bs[r * 32 + es * 8];
            }
            // staggered prefetch: (t,s0)->stage(t+1,s1); (t,s1)->stage(t+2,s0).
            // WAR-safe: target slice's readers finished before this phase's barrier.
            if (ks == 0) { if (t + 1 < NT) stage(t + 1, 1); }
            else         { if (t + 2 < NT) stage(t + 2, 0); }

            waitlgkm0();
            __builtin_amdgcn_sched_barrier(0);
            __builtin_amdgcn_s_setprio(1);
            #pragma unroll
            for (int m = 0; m < 8; ++m)
                #pragma unroll
                for (int n = 0; n < NRW; ++n)
                    acc[m][n] = __builtin_amdgcn_mfma_f32_16x16x32_f16(af[m], bf[n], acc[m][n], 0, 0, 0);
            __builtin_amdgcn_s_setprio(0);
        }
    }

    // epilogue: C/D layout col=lane&15, row=(lane>>4)*4+i
    const int row0 = blockIdx.y * BM + wr * 128;
    const int col0 = blockIdx.x * BN + wc * (BN / 4);
    #pragma unroll
    for (int m = 0; m < 8; ++m)
        #pragma unroll
        for (int n = 0; n < NRW; ++n)
            #pragma unroll
            for (int i = 0; i < 4; ++i) {
                int r = row0 + m * 16 + fq * 4 + i;
                int c = col0 + n * 16 + fr;
                float v = acc[m][n][i];
                if constexpr (BIAS_MODE == 1) v += bias[c];
                if constexpr (BIAS_MODE == 2) v += bias[r];
                if constexpr (OUT_F16)
                    ((unsigned short*)Cptr + bz * cBatch)[(long long)r * ldc + c] = f2h_bits(v);
                else
                    ((float*)Cptr + bz * cBatch)[(long long)r * ldc + c] = v;
            }
}

// ===================== fallback 3-stage pipe (nb==1 only) =====================
template<int BM, int BN, int WM, int WN, int BIAS_MODE, bool OUT_F16>
__global__ __launch_bounds__(WM * WN * 64) void gemm_pipe(
    const unsigned short* __restrict__ A, int lda,
    const unsigned short* __restrict__ Bt, int ldb,
    const float* __restrict__ bias,
    void* __restrict__ Cptr, int ldc, int K,
    long long aBatch, long long bBatch, long long cBatch)
{
    constexpr int THREADS = WM * WN * 64;
    constexpr int MR = BM / (WM * 16);
    constexpr int NR = BN / (WN * 16);
    constexpr int SA = (BM * 4) / THREADS;
    constexpr int SB = (BN * 4) / THREADS;
    constexpr int SN = SA + SB;

    __shared__ unsigned short La[3][BM][32];
    __shared__ unsigned short Lb[3][BN][32];

    const int tid = threadIdx.x, lane = tid & 63, wave = tid >> 6;
    const int wr = wave / WN, wc = wave % WN;
    const int fr = lane & 15, fq = lane >> 4;

    const long long bz = blockIdx.z;
    const unsigned short* Ab = A + bz * aBatch + (long long)(blockIdx.y * BM) * lda;
    const unsigned short* Bb = Bt + bz * bBatch + (long long)(blockIdx.x * BN) * ldb;

    const unsigned short* sA[SA]; int oA[SA];
    #pragma unroll
    for (int i = 0; i < SA; ++i) {
        int c = i * THREADS + tid;
        sA[i] = Ab + (long long)(c >> 2) * lda + (c & 3) * 8;
        oA[i] = (i * THREADS + wave * 64) * 16;
    }
    const unsigned short* sB[SB]; int oB[SB];
    #pragma unroll
    for (int i = 0; i < SB; ++i) {
        int c = i * THREADS + tid;
        sB[i] = Bb + (long long)(c >> 2) * ldb + (c & 3) * 8;
        oB[i] = (i * THREADS + wave * 64) * 16;
    }

    auto stage = [&](int buf, int k0) {
        #pragma unroll
        for (int i = 0; i < SA; ++i) gload16(sA[i] + k0, (char*)&La[buf][0][0] + oA[i]);
        #pragma unroll
        for (int i = 0; i < SB; ++i) gload16(sB[i] + k0, (char*)&Lb[buf][0][0] + oB[i]);
    };

    const int NT = K / 32;
    stage(0, 0);
    stage(1, 32);
    __builtin_amdgcn_sched_barrier(0);
    waitvm<SN>();
    __builtin_amdgcn_s_barrier();
    __builtin_amdgcn_sched_barrier(0);

    f32x4 acc[MR][NR] = {};
    int bsel = 0;

    for (int t = 0; t < NT; ++t) {
        f16x8 af[MR], bf[NR];
        #pragma unroll
        for (int m = 0; m < MR; ++m)
            af[m] = *(const f16x8*)&La[bsel][wr * (MR * 16) + m * 16 + fr][fq * 8];
        #pragma unroll
        for (int n = 0; n < NR; ++n)
            bf[n] = *(const f16x8*)&Lb[bsel][wc * (NR * 16) + n * 16 + fr][fq * 8];

        if (t + 2 < NT) {
            int b2 = bsel - 1; if (b2 < 0) b2 += 3;
            stage(b2, (t + 2) * 32);
        }

        __builtin_amdgcn_s_setprio(1);
        #pragma unroll
        for (int m = 0; m < MR; ++m)
            #pragma unroll
            for (int n = 0; n < NR; ++n)
                acc[m][n] = __builtin_amdgcn_mfma_f32_16x16x32_f16(af[m], bf[n], acc[m][n], 0, 0, 0);
        __builtin_amdgcn_s_setprio(0);

        __builtin_amdgcn_sched_barrier(0);
        waitvm<SN>();
        __builtin_amdgcn_s_barrier();
        __builtin_amdgcn_sched_barrier(0);

        bsel = (bsel == 2) ? 0 : bsel + 1;
    }

    const int row0 = blockIdx.y * BM + wr * (MR * 16);
    const int col0 = blockIdx.x * BN + wc * (NR * 16);
    #pragma unroll
    for (int m = 0; m < MR; ++m)
        #pragma unroll
        for (int n = 0; n < NR; ++n)
            #pragma unroll
            for (int i = 0; i < 4; ++i) {
                int r = row0 + m * 16 + fq * 4 + i;
                int c = col0 + n * 16 + fr;
                float v = acc[m][n][i];
                if constexpr (BIAS_MODE == 1) v += bias[c];
                if constexpr (BIAS_MODE == 2) v += bias[r];
                if constexpr (OUT_F16)
                    ((unsigned short*)Cptr + bz * cBatch)[(long long)r * ldc + c] = f2h_bits(v);
                else
                    ((float*)Cptr + bz * cBatch)[(long long)r * ldc + c] = v;
            }
}

// ===================== small kernels =====================
__global__ __launch_bounds__(256) void cvt_f32_f16(const float* __restrict__ in,
                                                   unsigned short* __restrict__ out, int n8)
{
    int i = blockIdx.x * blockDim.x + threadIdx.x;
    if (i >= n8) return;
    const float4* p = (const float4*)in + (long long)i * 2;
    float4 a = p[0], b = p[1];
    ushort4 o0, o1;
    o0.x = f2h_bits(a.x); o0.y = f2h_bits(a.y); o0.z = f2h_bits(a.z); o0.w = f2h_bits(a.w);
    o1.x = f2h_bits(b.x); o1.y = f2h_bits(b.y); o1.z = f2h_bits(b.z); o1.w = f2h_bits(b.w);
    ushort4* o = (ushort4*)out + (long long)i * 2;
    o[0] = o0; o[1] = o1;
}

__global__ void transpose_cvt(const float* __restrict__ in, unsigned short* __restrict__ out,
                              int R, int C)
{
    __shared__ unsigned short t[32][33];
    const int bx = blockIdx.x * 32;
    const int by = blockIdx.y * 32;
    const int xT = threadIdx.x, yT = threadIdx.y;  // block (32,8)
    #pragma unroll
    for (int i = 0; i < 32; i += 8)
        t[yT + i][xT] = f2h_bits(in[(long long)(by + yT + i) * C + bx + xT]);
    __syncthreads();
    #pragma unroll
    for (int i = 0; i < 32; i += 8)
        out[(long long)(bx + yT + i) * R + by + xT] = t[xT][yT + i];
}

// vt[b][e][j] = qkv[b*SEQ + j][2048 + e]
__global__ void vtrans(const unsigned short* __restrict__ qkv, unsigned short* __restrict__ vt)
{
    __shared__ unsigned short t[32][33];
    const long long b = blockIdx.z;
    const int bx = blockIdx.x * 32;   // e
    const int by = blockIdx.y * 32;   // j
    const int xT = threadIdx.x, yT = threadIdx.y;
    const unsigned short* in = qkv + b * SEQ * 3072 + 2048;
    #pragma unroll
    for (int i = 0; i < 32; i += 8)
        t[yT + i][xT] = in[(long long)(by + yT + i) * 3072 + bx + xT];
    __syncthreads();
    unsigned short* o = vt + b * HIDDEN * SEQ;
    #pragma unroll
    for (int i = 0; i < 32; i += 8)
        o[(long long)(bx + yT + i) * SEQ + by + xT] = t[xT][yT + i];
}

__global__ void concat_bias3(const float* __restrict__ bq, const float* __restrict__ bk,
                             const float* __restrict__ bv, float* __restrict__ cb)
{
    int i = threadIdx.x;  // 1024 threads
    cb[i] = bq[i];
    cb[HIDDEN + i] = bk[i];
    cb[2 * HIDDEN + i] = bv[i];
}

__global__ __launch_bounds__(256) void softmax_inplace(float* __restrict__ S)
{
    const int tid = threadIdx.x;
    float* row = S + (long long)blockIdx.x * SEQ;
    float4 a = ((const float4*)row)[tid];
    float4 b = ((const float4*)row)[tid + 256];
    float vv[8] = {a.x, a.y, a.z, a.w, b.x, b.y, b.z, b.w};

    float mx = vv[0];
    #pragma unroll
    for (int j = 1; j < 8; ++j) mx = fmaxf(mx, vv[j]);
    #pragma unroll
    for (int o = 32; o > 0; o >>= 1) mx = fmaxf(mx, __shfl_xor(mx, o));
    __shared__ float redm[4], reds[4];
    if ((tid & 63) == 0) redm[tid >> 6] = mx;
    __syncthreads();
    mx = fmaxf(fmaxf(redm[0], redm[1]), fmaxf(redm[2], redm[3]));

    float ev[8], sum = 0.f;
    #pragma unroll
    for (int j = 0; j < 8; ++j) { ev[j] = __expf(vv[j] - mx); sum += ev[j]; }
    #pragma unroll
    for (int o = 32; o > 0; o >>= 1) sum += __shfl_xor(sum, o);
    if ((tid & 63) == 0) reds[tid >> 6] = sum;
    __syncthreads();
    sum = reds[0] + reds[1] + reds[2] + reds[3];
    float inv = 1.0f / sum;

    unsigned short* rb = (unsigned short*)row;
    ushort4 o0, o1;
    o0.x = f2h_bits(ev[0] * inv); o0.y = f2h_bits(ev[1] * inv);
    o0.z = f2h_bits(ev[2] * inv); o0.w = f2h_bits(ev[3] * inv);
    o1.x = f2h_bits(ev[4] * inv); o1.y = f2h_bits(ev[5] * inv);
    o1.z = f2h_bits(ev[6] * inv); o1.w = f2h_bits(ev[7] * inv);
    *(ushort4*)&rb[(long long)tid * 4] = o0;
    *(ushort4*)&rb[((long long)tid + 256) * 4] = o1;
}

// ===================== launch =====================
extern "C" void kernel_launch(void* const* d_in, const int* in_sizes, int n_in,
                              void* d_out, int out_size, void* d_ws, size_t ws_size,
                              hipStream_t stream)
{
    (void)in_sizes; (void)n_in; (void)out_size;
    const float* x  = (const float*)d_in[0];
    const float* Wq = (const float*)d_in[1];
    const float* bq = (const float*)d_in[2];
    const float* Wk = (const float*)d_in[3];
    const float* bk = (const float*)d_in[4];
    const float* Wv = (const float*)d_in[5];
    const float* bv = (const float*)d_in[6];
    float* out = (float*)d_out;

    (void)hipFuncSetAttribute(reinterpret_cast<const void*>(&gemm8p<256, 1, true>),
                              hipFuncAttributeMaxDynamicSharedMemorySize, 131072);
    (void)hipFuncSetAttribute(reinterpret_cast<const void*>(&gemm8p<256, 0, false>),
                              hipFuncAttributeMaxDynamicSharedMemorySize, 131072);
    (void)hipFuncSetAttribute(reinterpret_cast<const void*>(&gemm8p<128, 0, false>),
                              hipFuncAttributeMaxDynamicSharedMemorySize, 98304);

    char* ws = (char*)d_ws;
    const long long MTOT = (long long)NB * SEQ;  // 8192

    // region0 [0,16MiB): xh, then (after proj) vt.  region1 [16,64MiB): qkv.
    // region2 [64MiB,...): wt+cb during proj, then S (ngrp batches of f32 scores).
    unsigned short* xh  = (unsigned short*)ws;
    unsigned short* vt  = (unsigned short*)ws;
    unsigned short* qkv = (unsigned short*)(ws + (size_t)16 * 1024 * 1024);
    char* region2 = ws + (size_t)64 * 1024 * 1024;
    unsigned short* wt = (unsigned short*)region2;
    float* cb = (float*)(region2 + (size_t)3 * HIDDEN * HIDDEN * 2);
    float* S = (float*)region2;
    const size_t sPer = (size_t)SEQ * SEQ * 4;
    size_t rem = ws_size > (size_t)64 * 1024 * 1024 ? ws_size - (size_t)64 * 1024 * 1024 : 0;
    int ngrp = (int)(rem / sPer);
    if (ngrp > NB) ngrp = NB;
    if (ngrp == 3) ngrp = 2;
    if (ngrp < 1) ngrp = 1;

    {
        int n8 = (int)(MTOT * HIDDEN / 8);
        cvt_f32_f16<<<dim3((n8 + 255) / 256), 256, 0, stream>>>(x, xh, n8);
    }
    dim3 tb(32, 8), tg(HIDDEN / 32, HIDDEN / 32);
    transpose_cvt<<<tg, tb, 0, stream>>>(Wq, wt,                       HIDDEN, HIDDEN);
    transpose_cvt<<<tg, tb, 0, stream>>>(Wk, wt +     HIDDEN * HIDDEN, HIDDEN, HIDDEN);
    transpose_cvt<<<tg, tb, 0, stream>>>(Wv, wt + 2 * HIDDEN * HIDDEN, HIDDEN, HIDDEN);
    concat_bias3<<<1, 1024, 0, stream>>>(bq, bk, bv, cb);

    // qkv[8192][3072] = xh @ [Wq|Wk|Wv] + [bq|bk|bv]   (384 blocks)
    gemm8p<256, 1, true><<<dim3(3072 / 256, (unsigned)(MTOT / 256), 1), 512, 131072, stream>>>(
        xh, HIDDEN, wt, HIDDEN, cb, qkv, 3072, HIDDEN, 0, 0, 0);

    // vt[b][1024][2048] from v-slice of qkv (xh is dead now; same region)
    vtrans<<<dim3(HIDDEN / 32, SEQ / 32, NB), tb, 0, stream>>>(qkv, vt);

    for (int b0 = 0; b0 < NB; b0 += ngrp) {
        int nb = (NB - b0 < ngrp) ? NB - b0 : ngrp;
        const unsigned short* q  = qkv + (long long)b0 * SEQ * 3072;
        const unsigned short* km = q + HIDDEN;
        if (nb >= 2) {
            gemm8p<256, 0, false><<<dim3(SEQ / 256, SEQ / 256, nb), 512, 131072, stream>>>(
                q, 3072, km, 3072, nullptr, S, SEQ, HIDDEN,
                (long long)SEQ * 3072, (long long)SEQ * 3072, (long long)SEQ * SEQ);
        } else {
            gemm_pipe<128, 128, 2, 2, 0, false><<<dim3(SEQ / 128, SEQ / 128, 1), 256, 0, stream>>>(
                q, 3072, km, 3072, nullptr, S, SEQ, HIDDEN, 0, 0, 0);
        }
        softmax_inplace<<<dim3(nb * SEQ), 256, 0, stream>>>(S);
        const unsigned short* P = (const unsigned short*)S;
        const unsigned short* Bv = vt + (long long)b0 * HIDDEN * SEQ;
        float* Ob = out + (long long)b0 * SEQ * HIDDEN;
        if (nb >= 2) {
            gemm8p<128, 0, false><<<dim3(HIDDEN / 128, SEQ / 256, nb), 512, 98304, stream>>>(
                P, 2 * SEQ, Bv, SEQ, nullptr, Ob, HIDDEN, SEQ,
                (long long)SEQ * 2 * SEQ, (long long)HIDDEN * SEQ, (long long)SEQ * HIDDEN);
        } else {
            gemm_pipe<64, 128, 2, 2, 0, false><<<dim3(HIDDEN / 128, SEQ / 64, 1), 256, 0, stream>>>(
                P, 2 * SEQ, Bv, SEQ, nullptr, Ob, HIDDEN, SEQ, 0, 0, 0);
        }
    }
}